// Round 6
// baseline (454.457 us; speedup 1.0000x reference)
//
#include <hip/hip_runtime.h>
#include <math.h>

#define NN 50000
#define NE 800000
#define TM 16

typedef _Float16 half4v __attribute__((ext_vector_type(4)));
typedef _Float16 half8v __attribute__((ext_vector_type(8)));
typedef float f32x4 __attribute__((ext_vector_type(4)));

__device__ __forceinline__ float relu(float v) { return fmaxf(v, 0.0f); }

// ---- degree count over dst ----
__global__ __launch_bounds__(256) void k_deg(const int* __restrict__ ei,
                                             int* __restrict__ deg) {
  int e = blockIdx.x * 256 + threadIdx.x;
  if (e < NE) atomicAdd(&deg[ei[NE + e]], 1);
}

// ---- d^-1/2 ----
__global__ __launch_bounds__(256) void k_dinv(const int* __restrict__ deg,
                                              float* __restrict__ dinv) {
  int i = blockIdx.x * 256 + threadIdx.x;
  if (i < NN) {
    int d = deg[i];
    dinv[i] = d > 0 ? 1.0f / sqrtf((float)d) : 0.0f;
  }
}

// ---- exclusive scan of deg -> rowptr (single 1024-thread block) ----
__global__ __launch_bounds__(1024) void k_scan(const int* __restrict__ deg,
                                               int* __restrict__ rowptr) {
  __shared__ int swave[16];
  __shared__ int scarry;
  const int tid = threadIdx.x;
  const int lane = tid & 63;
  const int wid = tid >> 6;
  if (tid == 0) scarry = 0;
  __syncthreads();
  for (int base = 0; base < NN; base += 1024) {
    int i = base + tid;
    int v = (i < NN) ? deg[i] : 0;
    int sum = v;
#pragma unroll
    for (int off = 1; off < 64; off <<= 1) {
      int t = __shfl_up(sum, off);
      if (lane >= off) sum += t;
    }
    if (lane == 63) swave[wid] = sum;
    __syncthreads();
    int wbase = 0;
    for (int w = 0; w < wid; ++w) wbase += swave[w];
    int carry = scarry;
    if (i < NN) rowptr[i] = carry + wbase + sum - v;
    __syncthreads();
    if (tid == 1023) scarry = carry + wbase + sum;
    __syncthreads();
  }
  if (tid == 0) rowptr[NN] = scarry;
}

// ---- CSR fill + edge weights ----
__global__ __launch_bounds__(256) void k_fill(const int* __restrict__ ei,
                                              const float* __restrict__ dinv,
                                              const int* __restrict__ rowptr,
                                              int* __restrict__ fill,
                                              int* __restrict__ col,
                                              float* __restrict__ wgt) {
  int e = blockIdx.x * 256 + threadIdx.x;
  if (e < NE) {
    int s = ei[e];
    int d = ei[NE + e];
    float w = dinv[s] * dinv[d] * 0.5f;
    int pos = rowptr[d] + atomicAdd(&fill[d], 1);
    col[pos] = s;
    wgt[pos] = w;
  }
}

// ---- x (f32) -> xh (f16) ----
__global__ __launch_bounds__(256) void k_x2h(const float* __restrict__ x,
                                             _Float16* __restrict__ xh) {
  int i = blockIdx.x * 256 + threadIdx.x;
  if (i < NN * 32) {
    float4 v = ((const float4*)x)[i];
    half4v h;
    h[0] = (_Float16)v.x; h[1] = (_Float16)v.y;
    h[2] = (_Float16)v.z; h[3] = (_Float16)v.w;
    ((half4v*)xh)[i] = h;
  }
}

// ---- one hop, XCD-sliced: each XCD pair owns a 32-col slice (3.2 MB, L2-fit)
// grid = 391*8 blocks; bid&7 -> xcd; slice = xcd>>1; 4 lanes/node, 64 nodes/blk
__global__ __launch_bounds__(256) void k_hop_s(const _Float16* __restrict__ in,
                                               _Float16* __restrict__ out,
                                               const int* __restrict__ rowptr,
                                               const int* __restrict__ col,
                                               const float* __restrict__ wgt) {
  const int bid = blockIdx.x;
  const int xcd = bid & 7;
  const int s = xcd >> 1;         // column slice 0..3
  const int halfp = xcd & 1;      // which half of the node range
  const int nb = (bid >> 3) * 2 + halfp;  // node block 0..781
  const int t = threadIdx.x;
  const int node = nb * 64 + (t >> 2);
  const int lane = t & 3;
  if (node >= NN) return;
  const half8v* in8 = (const half8v*)in;  // row = 16 x half8v
  const int coff = s * 4 + lane;          // this lane's 16B chunk in the row
  const size_t self = (size_t)node * 16 + coff;
  half8v a = in8[self];
  float acc[8];
#pragma unroll
  for (int j = 0; j < 8; ++j) acc[j] = 0.5f * (float)a[j];
  int e = rowptr[node], e1 = rowptr[node + 1];
  for (; e + 4 <= e1; e += 4) {
    int c0 = col[e], c1 = col[e + 1], c2 = col[e + 2], c3 = col[e + 3];
    float w0 = wgt[e], w1 = wgt[e + 1], w2 = wgt[e + 2], w3 = wgt[e + 3];
    half8v v0 = in8[(size_t)c0 * 16 + coff];
    half8v v1 = in8[(size_t)c1 * 16 + coff];
    half8v v2 = in8[(size_t)c2 * 16 + coff];
    half8v v3 = in8[(size_t)c3 * 16 + coff];
#pragma unroll
    for (int j = 0; j < 8; ++j)
      acc[j] += w0 * (float)v0[j] + w1 * (float)v1[j] +
                w2 * (float)v2[j] + w3 * (float)v3[j];
  }
  for (; e < e1; ++e) {
    float w = wgt[e];
    half8v v = in8[(size_t)col[e] * 16 + coff];
#pragma unroll
    for (int j = 0; j < 8; ++j) acc[j] += w * (float)v[j];
  }
  half8v r;
#pragma unroll
  for (int j = 0; j < 8; ++j) r[j] = (_Float16)acc[j];
  ((half8v*)out)[self] = r;
}

// ---- prep: weights -> f16 fragment-order [m][ct(8)][ks(4)][lane(64)][8] ----
__global__ __launch_bounds__(256) void k_prep(const float* __restrict__ W_low,
                                              const float* __restrict__ W_band,
                                              const float* __restrict__ W_mlp,
                                              _Float16* __restrict__ WTs) {
  int m = blockIdx.x;  // 0..6 channels, 7..8 mlp chunks
  const float* src;
  if (m < 4)      src = W_low + m * 16384;
  else if (m < 7) src = W_band + (m - 4) * 16384;
  else            src = W_mlp + (m - 7) * 16384;
  _Float16* dst = WTs + (size_t)m * 16384;
  for (int s = threadIdx.x; s < 2048; s += 256) {
    int ct = s >> 8;          // col tile 0..7
    int ks = (s >> 6) & 3;    // k step 0..3
    int lane = s & 63;
    int mcol = lane & 15, kg = lane >> 4;
    int colc = ct * 16 + mcol;
    int k0 = ks * 32 + 4 * kg;
    _Float16* d = dst + (size_t)s * 8;
#pragma unroll
    for (int j = 0; j < 4; ++j) d[j] = (_Float16)src[(k0 + j) * 128 + colc];
#pragma unroll
    for (int j = 0; j < 4; ++j) d[4 + j] = (_Float16)src[(k0 + 16 + j) * 128 + colc];
  }
}

// ---- fused MFMA: 7-channel GEMM + attention + MLP; coalesced B frags ----
__global__ __launch_bounds__(256, 3) void k_fused(
    const _Float16* __restrict__ xh, const _Float16* __restrict__ a1,
    const _Float16* __restrict__ a2, const _Float16* __restrict__ a4,
    const _Float16* __restrict__ WTs,
    const float* __restrict__ b_low, const float* __restrict__ b_band,
    const float* __restrict__ apre_l, const float* __restrict__ ach_l,
    const float* __restrict__ apre_b, const float* __restrict__ ach_b,
    const float* __restrict__ b_mlp, float* __restrict__ out) {
  __shared__ _Float16 sH[7][TM][136]; // channel outputs  30464 B
  __shared__ _Float16 sV[TM][264];    // MLP input         8448 B

  const int tid = threadIdx.x;
  const int wid = tid >> 6;
  const int lane = tid & 63;
  const int mrow = lane & 15;   // node row in tile / out col in 16-tile
  const int kg = lane >> 4;     // k-group 0..3
  const int node0 = blockIdx.x * TM;
  const int colw = wid * 32;    // wave's 32-col slice (coltiles 2wid, 2wid+1)

  // ---- A fragments for the 4 base aggregates (held in registers) ----
  half8v base[4][4];  // [array][ks]
  {
    const _Float16* arrs[4] = {xh, a1, a2, a4};
#pragma unroll
    for (int t = 0; t < 4; ++t) {
      const _Float16* p = arrs[t] + (size_t)(node0 + mrow) * 128;
#pragma unroll
      for (int ks = 0; ks < 4; ++ks) {
        half4v lo = *(const half4v*)&p[ks * 32 + 4 * kg];
        half4v hi = *(const half4v*)&p[ks * 32 + 4 * kg + 16];
        base[t][ks] = __builtin_shufflevector(lo, hi, 0, 1, 2, 3, 4, 5, 6, 7);
      }
    }
  }

  // ---- 7 channel GEMMs, B frags coalesced from global (L2-hot) ----
#pragma unroll
  for (int c = 0; c < 7; ++c) {
    const int ia = (c < 4) ? c : (c - 4);
    const int ib = (c < 4) ? -1 : (c - 3);
    const _Float16* wc = WTs + (size_t)c * 16384;
    f32x4 acc0 = {0.f, 0.f, 0.f, 0.f}, acc1 = {0.f, 0.f, 0.f, 0.f};
#pragma unroll
    for (int ks = 0; ks < 4; ++ks) {
      half8v af = (ib < 0) ? base[ia][ks] : (base[ia][ks] - base[ib][ks]);
      half8v bf0 = *(const half8v*)&wc[(size_t)(2 * wid) * 2048 + ks * 512 + lane * 8];
      half8v bf1 = *(const half8v*)&wc[(size_t)(2 * wid + 1) * 2048 + ks * 512 + lane * 8];
      acc0 = __builtin_amdgcn_mfma_f32_16x16x32_f16(af, bf0, acc0, 0, 0, 0);
      acc1 = __builtin_amdgcn_mfma_f32_16x16x32_f16(af, bf1, acc1, 0, 0, 0);
    }
    const float* bias = (c < 4) ? (b_low + c * 128) : (b_band + (c - 4) * 128);
    float bv0 = bias[colw + mrow];
    float bv1 = bias[colw + 16 + mrow];
#pragma unroll
    for (int r = 0; r < 4; ++r) {
      sH[c][4 * kg + r][colw + mrow] = (_Float16)(acc0[r] + bv0);
      sH[c][4 * kg + r][colw + 16 + mrow] = (_Float16)(acc1[r] + bv1);
    }
  }
  __syncthreads();

  // ---- attention: 16 threads per node, 8 cols each ----
  {
    const int n = tid >> 4;
    const int cb = (tid & 15) * 8;
    float apl[8], acl[8], apb[8], acb[8];
#pragma unroll
    for (int j = 0; j < 8; ++j) {
      apl[j] = apre_l[cb + j]; acl[j] = ach_l[cb + j];
      apb[j] = apre_b[cb + j]; acb[j] = ach_b[cb + j];
    }
    float dpl = 0.f, dpb = 0.f;
    float sarr[7];
#pragma unroll
    for (int c = 0; c < 7; ++c) {
      float sp = 0.f, sc = 0.f;
#pragma unroll
      for (int j = 0; j < 8; ++j) {
        float h = (float)sH[c][n][cb + j];
        float r = relu(h);
        if (c < 4) { sp += r * apl[j]; sc += r * acl[j]; }
        else       { sp += r * apb[j]; sc += r * acb[j]; }
      }
      if (c < 4) dpl += sp; else dpb += sp;
      sarr[c] = sc;
    }
    dpl *= 0.25f;
    dpb *= (1.0f / 3.0f);
#pragma unroll
    for (int m = 1; m <= 8; m <<= 1) {
      dpl += __shfl_xor(dpl, m);
      dpb += __shfl_xor(dpb, m);
#pragma unroll
      for (int c = 0; c < 7; ++c) sarr[c] += __shfl_xor(sarr[c], m);
    }
    float lg[7];
#pragma unroll
    for (int c = 0; c < 7; ++c)
      lg[c] = relu((c < 4 ? dpl : dpb) + sarr[c]);
    float ml = fmaxf(fmaxf(lg[0], lg[1]), fmaxf(lg[2], lg[3]));
    float e0 = expf(lg[0] - ml), e1 = expf(lg[1] - ml);
    float e2 = expf(lg[2] - ml), e3 = expf(lg[3] - ml);
    float invl = 1.0f / (e0 + e1 + e2 + e3);
    float mb = fmaxf(fmaxf(lg[4], lg[5]), lg[6]);
    float f4 = expf(lg[4] - mb), f5 = expf(lg[5] - mb), f6 = expf(lg[6] - mb);
    float invb = 1.0f / (f4 + f5 + f6);
    float al[7];
    al[0] = e0 * invl; al[1] = e1 * invl; al[2] = e2 * invl; al[3] = e3 * invl;
    al[4] = f4 * invb; al[5] = f5 * invb; al[6] = f6 * invb;
    half8v vl8, vb8;
#pragma unroll
    for (int j = 0; j < 8; ++j) {
      float vl = 0.f, vb = 0.f;
#pragma unroll
      for (int c = 0; c < 4; ++c) vl += al[c] * (float)sH[c][n][cb + j];
#pragma unroll
      for (int c = 4; c < 7; ++c) vb += al[c] * (float)sH[c][n][cb + j];
      vl8[j] = (_Float16)vl;
      vb8[j] = (_Float16)vb;
    }
    *(half8v*)&sV[n][cb] = vl8;
    *(half8v*)&sV[n][128 + cb] = vb8;
  }
  __syncthreads();

  // ---- MLP: [TM,256] @ [256,128], coalesced B frags ----
  f32x4 m0 = {0.f, 0.f, 0.f, 0.f}, m1 = {0.f, 0.f, 0.f, 0.f};
#pragma unroll
  for (int hh = 0; hh < 2; ++hh) {
    const _Float16* wm = WTs + (size_t)(7 + hh) * 16384;
#pragma unroll
    for (int ks = 0; ks < 4; ++ks) {
      int ka = hh * 128 + ks * 32 + 4 * kg;
      half4v aa = *(const half4v*)&sV[mrow][ka];
      half4v ab = *(const half4v*)&sV[mrow][ka + 16];
      half8v af = __builtin_shufflevector(aa, ab, 0, 1, 2, 3, 4, 5, 6, 7);
      half8v bf0 = *(const half8v*)&wm[(size_t)(2 * wid) * 2048 + ks * 512 + lane * 8];
      half8v bf1 = *(const half8v*)&wm[(size_t)(2 * wid + 1) * 2048 + ks * 512 + lane * 8];
      m0 = __builtin_amdgcn_mfma_f32_16x16x32_f16(af, bf0, m0, 0, 0, 0);
      m1 = __builtin_amdgcn_mfma_f32_16x16x32_f16(af, bf1, m1, 0, 0, 0);
    }
  }
  float bm0 = b_mlp[colw + mrow];
  float bm1 = b_mlp[colw + 16 + mrow];
#pragma unroll
  for (int r = 0; r < 4; ++r) {
    out[(size_t)(node0 + 4 * kg + r) * 128 + colw + mrow] = m0[r] + bm0;
    out[(size_t)(node0 + 4 * kg + r) * 128 + colw + 16 + mrow] = m1[r] + bm1;
  }
}

extern "C" void kernel_launch(void* const* d_in, const int* in_sizes, int n_in,
                              void* d_out, int out_size, void* d_ws, size_t ws_size,
                              hipStream_t stream) {
  const float* x      = (const float*)d_in[0];
  const int* ei       = (const int*)d_in[1];
  const float* W_low  = (const float*)d_in[2];
  const float* b_low  = (const float*)d_in[3];
  const float* W_band = (const float*)d_in[4];
  const float* b_band = (const float*)d_in[5];
  const float* apre_l = (const float*)d_in[6];
  const float* ach_l  = (const float*)d_in[7];
  const float* apre_b = (const float*)d_in[8];
  const float* ach_b  = (const float*)d_in[9];
  const float* W_mlp  = (const float*)d_in[10];
  const float* b_mlp  = (const float*)d_in[11];
  float* out = (float*)d_out;

  char* ws = (char*)d_ws;
  size_t off = 0;
  auto take = [&](size_t bytes) -> void* {
    void* p = ws + off;
    off = (off + bytes + 255) & ~(size_t)255;
    return p;
  };
  int*   deg    = (int*)take((size_t)NN * 4);
  int*   fill   = (int*)take((size_t)NN * 4);
  size_t zero_bytes = off;  // deg + fill region
  float* dinv   = (float*)take((size_t)NN * 4);
  int*   rowptr = (int*)take((size_t)(NN + 1) * 4);
  int*   col    = (int*)take((size_t)NE * 4);
  float* wgt    = (float*)take((size_t)NE * 4);
  _Float16* xh  = (_Float16*)take((size_t)NN * 128 * 2);
  _Float16* a1h = (_Float16*)take((size_t)NN * 128 * 2);
  _Float16* a2h = (_Float16*)take((size_t)NN * 128 * 2);
  _Float16* a3h = (_Float16*)take((size_t)NN * 128 * 2);
  _Float16* a4h = (_Float16*)take((size_t)NN * 128 * 2);
  _Float16* WTs = (_Float16*)take((size_t)9 * 16384 * 2);
  (void)ws_size; (void)in_sizes; (void)n_in; (void)out_size;

  hipMemsetAsync(d_ws, 0, zero_bytes, stream);
  k_prep<<<9, 256, 0, stream>>>(W_low, W_band, W_mlp, WTs);
  k_x2h<<<(NN * 32 + 255) / 256, 256, 0, stream>>>(x, xh);
  k_deg<<<(NE + 255) / 256, 256, 0, stream>>>(ei, deg);
  k_dinv<<<(NN + 255) / 256, 256, 0, stream>>>(deg, dinv);
  k_scan<<<1, 1024, 0, stream>>>(deg, rowptr);
  k_fill<<<(NE + 255) / 256, 256, 0, stream>>>(ei, dinv, rowptr, fill, col, wgt);
  const int hop_grid = 391 * 8;  // 782 node-blocks x 4 slices, xcd-pinned
  k_hop_s<<<hop_grid, 256, 0, stream>>>(xh,  a1h, rowptr, col, wgt);
  k_hop_s<<<hop_grid, 256, 0, stream>>>(a1h, a2h, rowptr, col, wgt);
  k_hop_s<<<hop_grid, 256, 0, stream>>>(a2h, a3h, rowptr, col, wgt);
  k_hop_s<<<hop_grid, 256, 0, stream>>>(a3h, a4h, rowptr, col, wgt);
  k_fused<<<NN / TM, 256, 0, stream>>>(xh, a1h, a2h, a4h, WTs, b_low, b_band,
                                       apre_l, ach_l, apre_b, ach_b, b_mlp, out);
}

// Round 7
// 388.861 us; speedup vs baseline: 1.1687x; 1.1687x over previous
//
#include <hip/hip_runtime.h>
#include <math.h>

#define NN 50000
#define NE 800000
#define TM 16

typedef _Float16 half4v __attribute__((ext_vector_type(4)));
typedef _Float16 half8v __attribute__((ext_vector_type(8)));
typedef float f32x4 __attribute__((ext_vector_type(4)));

__device__ __forceinline__ float relu(float v) { return fmaxf(v, 0.0f); }

// ---- degree count over dst ----
__global__ __launch_bounds__(256) void k_deg(const int* __restrict__ ei,
                                             int* __restrict__ deg) {
  int e = blockIdx.x * 256 + threadIdx.x;
  if (e < NE) atomicAdd(&deg[ei[NE + e]], 1);
}

// ---- d^-1/2 ----
__global__ __launch_bounds__(256) void k_dinv(const int* __restrict__ deg,
                                              float* __restrict__ dinv) {
  int i = blockIdx.x * 256 + threadIdx.x;
  if (i < NN) {
    int d = deg[i];
    dinv[i] = d > 0 ? 1.0f / sqrtf((float)d) : 0.0f;
  }
}

// ---- exclusive scan of deg -> rowptr (single 1024-thread block) ----
__global__ __launch_bounds__(1024) void k_scan(const int* __restrict__ deg,
                                               int* __restrict__ rowptr) {
  __shared__ int swave[16];
  __shared__ int scarry;
  const int tid = threadIdx.x;
  const int lane = tid & 63;
  const int wid = tid >> 6;
  if (tid == 0) scarry = 0;
  __syncthreads();
  for (int base = 0; base < NN; base += 1024) {
    int i = base + tid;
    int v = (i < NN) ? deg[i] : 0;
    int sum = v;
#pragma unroll
    for (int off = 1; off < 64; off <<= 1) {
      int t = __shfl_up(sum, off);
      if (lane >= off) sum += t;
    }
    if (lane == 63) swave[wid] = sum;
    __syncthreads();
    int wbase = 0;
    for (int w = 0; w < wid; ++w) wbase += swave[w];
    int carry = scarry;
    if (i < NN) rowptr[i] = carry + wbase + sum - v;
    __syncthreads();
    if (tid == 1023) scarry = carry + wbase + sum;
    __syncthreads();
  }
  if (tid == 0) rowptr[NN] = scarry;
}

// ---- CSR fill + edge weights ----
__global__ __launch_bounds__(256) void k_fill(const int* __restrict__ ei,
                                              const float* __restrict__ dinv,
                                              const int* __restrict__ rowptr,
                                              int* __restrict__ fill,
                                              int* __restrict__ col,
                                              float* __restrict__ wgt) {
  int e = blockIdx.x * 256 + threadIdx.x;
  if (e < NE) {
    int s = ei[e];
    int d = ei[NE + e];
    float w = dinv[s] * dinv[d] * 0.5f;
    int pos = rowptr[d] + atomicAdd(&fill[d], 1);
    col[pos] = s;
    wgt[pos] = w;
  }
}

// ---- x (f32) -> xh (f16) ----
__global__ __launch_bounds__(256) void k_x2h(const float* __restrict__ x,
                                             _Float16* __restrict__ xh) {
  int i = blockIdx.x * 256 + threadIdx.x;
  if (i < NN * 32) {
    float4 v = ((const float4*)x)[i];
    half4v h;
    h[0] = (_Float16)v.x; h[1] = (_Float16)v.y;
    h[2] = (_Float16)v.z; h[3] = (_Float16)v.w;
    ((half4v*)xh)[i] = h;
  }
}

// ---- one hop: 16 lanes/node, 16B row chunks, f32 accumulate (R5 version) ----
__global__ __launch_bounds__(256) void k_hop16(const _Float16* __restrict__ in,
                                               _Float16* __restrict__ out,
                                               const int* __restrict__ rowptr,
                                               const int* __restrict__ col,
                                               const float* __restrict__ wgt) {
  int g = (blockIdx.x * 256 + threadIdx.x) >> 4;  // node, 16 threads/node
  int lane = threadIdx.x & 15;
  if (g >= NN) return;
  const half8v* in8 = (const half8v*)in;  // 16B per lane, 256B per row
  half8v a = in8[(size_t)g * 16 + lane];
  float acc[8];
#pragma unroll
  for (int j = 0; j < 8; ++j) acc[j] = 0.5f * (float)a[j];
  int e = rowptr[g], e1 = rowptr[g + 1];
  for (; e + 4 <= e1; e += 4) {
    int c0 = col[e], c1 = col[e + 1], c2 = col[e + 2], c3 = col[e + 3];
    float w0 = wgt[e], w1 = wgt[e + 1], w2 = wgt[e + 2], w3 = wgt[e + 3];
    half8v v0 = in8[(size_t)c0 * 16 + lane];
    half8v v1 = in8[(size_t)c1 * 16 + lane];
    half8v v2 = in8[(size_t)c2 * 16 + lane];
    half8v v3 = in8[(size_t)c3 * 16 + lane];
#pragma unroll
    for (int j = 0; j < 8; ++j)
      acc[j] += w0 * (float)v0[j] + w1 * (float)v1[j] +
                w2 * (float)v2[j] + w3 * (float)v3[j];
  }
  for (; e < e1; ++e) {
    float w = wgt[e];
    half8v v = in8[(size_t)col[e] * 16 + lane];
#pragma unroll
    for (int j = 0; j < 8; ++j) acc[j] += w * (float)v[j];
  }
  half8v r;
#pragma unroll
  for (int j = 0; j < 8; ++j) r[j] = (_Float16)acc[j];
  ((half8v*)out)[(size_t)g * 16 + lane] = r;
}

// ---- prep: weights -> f16 fragment-order [m][ct(8)][ks(4)][lane(64)][8] ----
__global__ __launch_bounds__(256) void k_prep(const float* __restrict__ W_low,
                                              const float* __restrict__ W_band,
                                              const float* __restrict__ W_mlp,
                                              _Float16* __restrict__ WTs) {
  int m = blockIdx.x;  // 0..6 channels, 7..8 mlp chunks
  const float* src;
  if (m < 4)      src = W_low + m * 16384;
  else if (m < 7) src = W_band + (m - 4) * 16384;
  else            src = W_mlp + (m - 7) * 16384;
  _Float16* dst = WTs + (size_t)m * 16384;
  for (int s = threadIdx.x; s < 2048; s += 256) {
    int ct = s >> 8;          // col tile 0..7
    int ks = (s >> 6) & 3;    // k step 0..3
    int lane = s & 63;
    int mcol = lane & 15, kg = lane >> 4;
    int colc = ct * 16 + mcol;
    int k0 = ks * 32 + 4 * kg;
    _Float16* d = dst + (size_t)s * 8;
#pragma unroll
    for (int j = 0; j < 4; ++j) d[j] = (_Float16)src[(k0 + j) * 128 + colc];
#pragma unroll
    for (int j = 0; j < 4; ++j) d[4 + j] = (_Float16)src[(k0 + 16 + j) * 128 + colc];
  }
}

// A-fragment load: 4 K-steps of the mrow-th node row of `src`
#define LOADF(dst, src)                                                        \
  {                                                                            \
    const _Float16* p_ = (src) + (size_t)(node0 + mrow) * 128;                 \
    _Pragma("unroll")                                                          \
    for (int ks = 0; ks < 4; ++ks) {                                           \
      half4v lo_ = *(const half4v*)&p_[ks * 32 + 4 * kg];                      \
      half4v hi_ = *(const half4v*)&p_[ks * 32 + 4 * kg + 16];                 \
      dst[ks] = __builtin_shufflevector(lo_, hi_, 0, 1, 2, 3, 4, 5, 6, 7);     \
    }                                                                          \
  }

// One channel GEMM: af per-ks expression, bias added into f32 acc, stored to
// h0[c]/h1[c] (c is a literal -> static register indexing).
#define CH_GEMM(c, AEXPR, BIASPTR)                                             \
  {                                                                            \
    const _Float16* wc_ = WTs + (size_t)(c) * 16384;                           \
    f32x4 A0_ = {0.f, 0.f, 0.f, 0.f}, A1_ = {0.f, 0.f, 0.f, 0.f};              \
    _Pragma("unroll")                                                          \
    for (int ks = 0; ks < 4; ++ks) {                                           \
      half8v af_ = (AEXPR);                                                    \
      half8v bf0_ = *(const half8v*)&wc_[(size_t)(2 * wid) * 2048 + ks * 512 + lane * 8];     \
      half8v bf1_ = *(const half8v*)&wc_[(size_t)(2 * wid + 1) * 2048 + ks * 512 + lane * 8]; \
      A0_ = __builtin_amdgcn_mfma_f32_16x16x32_f16(af_, bf0_, A0_, 0, 0, 0);   \
      A1_ = __builtin_amdgcn_mfma_f32_16x16x32_f16(af_, bf1_, A1_, 0, 0, 0);   \
    }                                                                          \
    float bv0_ = (BIASPTR)[colw + mrow], bv1_ = (BIASPTR)[colw + 16 + mrow];   \
    _Pragma("unroll")                                                          \
    for (int r = 0; r < 4; ++r) { A0_[r] += bv0_; A1_[r] += bv1_; }            \
    h0[c] = A0_; h1[c] = A1_;                                                  \
  }

// ---- fused MFMA: 7-channel GEMM (h in registers) + attention + MLP ----
__global__ __launch_bounds__(256, 4) void k_fused(
    const _Float16* __restrict__ xh, const _Float16* __restrict__ a1,
    const _Float16* __restrict__ a2, const _Float16* __restrict__ a4,
    const _Float16* __restrict__ WTs,
    const float* __restrict__ b_low, const float* __restrict__ b_band,
    const float* __restrict__ apre_l, const float* __restrict__ ach_l,
    const float* __restrict__ apre_b, const float* __restrict__ ach_b,
    const float* __restrict__ b_mlp, float* __restrict__ out) {
  __shared__ float pD[2][TM][4];     // [low|band][node][wave] pre-dot partials
  __shared__ float pS[7][TM][4];     // [chan][node][wave] chan-dot partials
  __shared__ float aB[TM][8];        // alpha per node (7 used)
  __shared__ _Float16 sV[TM][264];   // MLP input [node][256]+pad

  const int tid = threadIdx.x;
  const int wid = tid >> 6;
  const int lane = tid & 63;
  const int mrow = lane & 15;
  const int kg = lane >> 4;
  const int node0 = blockIdx.x * TM;
  const int colw = wid * 32;

  f32x4 h0[7], h1[7];  // per-channel outputs (bias included), static indexed
  half8v fA[4], fB[4];

  // rolling A-fragments; channel order shares arrays pairwise
  LOADF(fA, xh);
  CH_GEMM(0, fA[ks], b_low + 0 * 128);
  LOADF(fB, a1);
  CH_GEMM(4, fA[ks] - fB[ks], b_band + 0 * 128);
  CH_GEMM(1, fB[ks], b_low + 1 * 128);
  LOADF(fA, a2);
  CH_GEMM(5, fB[ks] - fA[ks], b_band + 1 * 128);
  CH_GEMM(2, fA[ks], b_low + 2 * 128);
  LOADF(fB, a4);
  CH_GEMM(6, fA[ks] - fB[ks], b_band + 2 * 128);
  CH_GEMM(3, fB[ks], b_low + 3 * 128);

  // ---- attention partials in-register ----
  const float apl0 = apre_l[colw + mrow], apl1 = apre_l[colw + 16 + mrow];
  const float acl0 = ach_l[colw + mrow],  acl1 = ach_l[colw + 16 + mrow];
  const float apb0 = apre_b[colw + mrow], apb1 = apre_b[colw + 16 + mrow];
  const float acb0 = ach_b[colw + mrow],  acb1 = ach_b[colw + 16 + mrow];

  float dpl[4] = {0.f, 0.f, 0.f, 0.f}, dpb[4] = {0.f, 0.f, 0.f, 0.f};
  float sc[7][4];
#pragma unroll
  for (int c = 0; c < 7; ++c) {
#pragma unroll
    for (int r = 0; r < 4; ++r) {
      float r0 = relu(h0[c][r]);
      float r1 = relu(h1[c][r]);
      if (c < 4) {
        dpl[r] += r0 * apl0 + r1 * apl1;
        sc[c][r] = r0 * acl0 + r1 * acl1;
      } else {
        dpb[r] += r0 * apb0 + r1 * apb1;
        sc[c][r] = r0 * acb0 + r1 * acb1;
      }
    }
  }
#pragma unroll
  for (int r = 0; r < 4; ++r) { dpl[r] *= 0.25f; dpb[r] *= (1.0f / 3.0f); }
  // reduce over the 16 mrow lanes (lane bits 0..3)
#pragma unroll
  for (int m = 1; m <= 8; m <<= 1) {
#pragma unroll
    for (int r = 0; r < 4; ++r) {
      dpl[r] += __shfl_xor(dpl[r], m);
      dpb[r] += __shfl_xor(dpb[r], m);
    }
#pragma unroll
    for (int c = 0; c < 7; ++c)
#pragma unroll
      for (int r = 0; r < 4; ++r) sc[c][r] += __shfl_xor(sc[c][r], m);
  }
  if (mrow == 0) {
#pragma unroll
    for (int r = 0; r < 4; ++r) {
      pD[0][4 * kg + r][wid] = dpl[r];
      pD[1][4 * kg + r][wid] = dpb[r];
#pragma unroll
      for (int c = 0; c < 7; ++c) pS[c][4 * kg + r][wid] = sc[c][r];
    }
  }
  __syncthreads();

  // ---- softmax over channels (one thread per node) ----
  if (tid < TM) {
    const int n = tid;
    float dl = pD[0][n][0] + pD[0][n][1] + pD[0][n][2] + pD[0][n][3];
    float db = pD[1][n][0] + pD[1][n][1] + pD[1][n][2] + pD[1][n][3];
    float lg[7];
#pragma unroll
    for (int c = 0; c < 7; ++c) {
      float s = pS[c][n][0] + pS[c][n][1] + pS[c][n][2] + pS[c][n][3];
      lg[c] = relu((c < 4 ? dl : db) + s);
    }
    float ml = fmaxf(fmaxf(lg[0], lg[1]), fmaxf(lg[2], lg[3]));
    float e0 = expf(lg[0] - ml), e1 = expf(lg[1] - ml);
    float e2 = expf(lg[2] - ml), e3 = expf(lg[3] - ml);
    float invl = 1.0f / (e0 + e1 + e2 + e3);
    float mb = fmaxf(fmaxf(lg[4], lg[5]), lg[6]);
    float f4 = expf(lg[4] - mb), f5 = expf(lg[5] - mb), f6 = expf(lg[6] - mb);
    float invb = 1.0f / (f4 + f5 + f6);
    aB[n][0] = e0 * invl; aB[n][1] = e1 * invl;
    aB[n][2] = e2 * invl; aB[n][3] = e3 * invl;
    aB[n][4] = f4 * invb; aB[n][5] = f5 * invb; aB[n][6] = f6 * invb;
  }
  __syncthreads();

  // ---- weighted sum straight from registers -> sV ----
#pragma unroll
  for (int r = 0; r < 4; ++r) {
    const int n = 4 * kg + r;
    float vl0 = 0.f, vl1 = 0.f, vb0 = 0.f, vb1 = 0.f;
#pragma unroll
    for (int c = 0; c < 4; ++c) {
      float a = aB[n][c];
      vl0 += a * h0[c][r];
      vl1 += a * h1[c][r];
    }
#pragma unroll
    for (int c = 4; c < 7; ++c) {
      float a = aB[n][c];
      vb0 += a * h0[c][r];
      vb1 += a * h1[c][r];
    }
    sV[n][colw + mrow] = (_Float16)vl0;
    sV[n][colw + 16 + mrow] = (_Float16)vl1;
    sV[n][128 + colw + mrow] = (_Float16)vb0;
    sV[n][128 + colw + 16 + mrow] = (_Float16)vb1;
  }
  __syncthreads();

  // ---- MLP: [TM,256] @ [256,128], coalesced B frags ----
  f32x4 m0 = {0.f, 0.f, 0.f, 0.f}, m1 = {0.f, 0.f, 0.f, 0.f};
#pragma unroll
  for (int hh = 0; hh < 2; ++hh) {
    const _Float16* wm = WTs + (size_t)(7 + hh) * 16384;
#pragma unroll
    for (int ks = 0; ks < 4; ++ks) {
      int ka = hh * 128 + ks * 32 + 4 * kg;
      half4v aa = *(const half4v*)&sV[mrow][ka];
      half4v ab = *(const half4v*)&sV[mrow][ka + 16];
      half8v af = __builtin_shufflevector(aa, ab, 0, 1, 2, 3, 4, 5, 6, 7);
      half8v bf0 = *(const half8v*)&wm[(size_t)(2 * wid) * 2048 + ks * 512 + lane * 8];
      half8v bf1 = *(const half8v*)&wm[(size_t)(2 * wid + 1) * 2048 + ks * 512 + lane * 8];
      m0 = __builtin_amdgcn_mfma_f32_16x16x32_f16(af, bf0, m0, 0, 0, 0);
      m1 = __builtin_amdgcn_mfma_f32_16x16x32_f16(af, bf1, m1, 0, 0, 0);
    }
  }
  float bm0 = b_mlp[colw + mrow];
  float bm1 = b_mlp[colw + 16 + mrow];
#pragma unroll
  for (int r = 0; r < 4; ++r) {
    out[(size_t)(node0 + 4 * kg + r) * 128 + colw + mrow] = m0[r] + bm0;
    out[(size_t)(node0 + 4 * kg + r) * 128 + colw + 16 + mrow] = m1[r] + bm1;
  }
}

extern "C" void kernel_launch(void* const* d_in, const int* in_sizes, int n_in,
                              void* d_out, int out_size, void* d_ws, size_t ws_size,
                              hipStream_t stream) {
  const float* x      = (const float*)d_in[0];
  const int* ei       = (const int*)d_in[1];
  const float* W_low  = (const float*)d_in[2];
  const float* b_low  = (const float*)d_in[3];
  const float* W_band = (const float*)d_in[4];
  const float* b_band = (const float*)d_in[5];
  const float* apre_l = (const float*)d_in[6];
  const float* ach_l  = (const float*)d_in[7];
  const float* apre_b = (const float*)d_in[8];
  const float* ach_b  = (const float*)d_in[9];
  const float* W_mlp  = (const float*)d_in[10];
  const float* b_mlp  = (const float*)d_in[11];
  float* out = (float*)d_out;

  char* ws = (char*)d_ws;
  size_t off = 0;
  auto take = [&](size_t bytes) -> void* {
    void* p = ws + off;
    off = (off + bytes + 255) & ~(size_t)255;
    return p;
  };
  int*   deg    = (int*)take((size_t)NN * 4);
  int*   fill   = (int*)take((size_t)NN * 4);
  size_t zero_bytes = off;  // deg + fill region
  float* dinv   = (float*)take((size_t)NN * 4);
  int*   rowptr = (int*)take((size_t)(NN + 1) * 4);
  int*   col    = (int*)take((size_t)NE * 4);
  float* wgt    = (float*)take((size_t)NE * 4);
  _Float16* xh  = (_Float16*)take((size_t)NN * 128 * 2);
  _Float16* a1h = (_Float16*)take((size_t)NN * 128 * 2);
  _Float16* a2h = (_Float16*)take((size_t)NN * 128 * 2);
  _Float16* a3h = (_Float16*)take((size_t)NN * 128 * 2);
  _Float16* a4h = (_Float16*)take((size_t)NN * 128 * 2);
  _Float16* WTs = (_Float16*)take((size_t)9 * 16384 * 2);
  (void)ws_size; (void)in_sizes; (void)n_in; (void)out_size;

  hipMemsetAsync(d_ws, 0, zero_bytes, stream);
  k_prep<<<9, 256, 0, stream>>>(W_low, W_band, W_mlp, WTs);
  k_x2h<<<(NN * 32 + 255) / 256, 256, 0, stream>>>(x, xh);
  k_deg<<<(NE + 255) / 256, 256, 0, stream>>>(ei, deg);
  k_dinv<<<(NN + 255) / 256, 256, 0, stream>>>(deg, dinv);
  k_scan<<<1, 1024, 0, stream>>>(deg, rowptr);
  k_fill<<<(NE + 255) / 256, 256, 0, stream>>>(ei, dinv, rowptr, fill, col, wgt);
  k_hop16<<<(NN * 16 + 255) / 256, 256, 0, stream>>>(xh,  a1h, rowptr, col, wgt);
  k_hop16<<<(NN * 16 + 255) / 256, 256, 0, stream>>>(a1h, a2h, rowptr, col, wgt);
  k_hop16<<<(NN * 16 + 255) / 256, 256, 0, stream>>>(a2h, a3h, rowptr, col, wgt);
  k_hop16<<<(NN * 16 + 255) / 256, 256, 0, stream>>>(a3h, a4h, rowptr, col, wgt);
  k_fused<<<NN / TM, 256, 0, stream>>>(xh, a1h, a2h, a4h, WTs, b_low, b_band,
                                       apre_l, ach_l, apre_b, ach_b, b_mlp, out);
}

// Round 8
// 376.306 us; speedup vs baseline: 1.2077x; 1.0334x over previous
//
#include <hip/hip_runtime.h>
#include <math.h>

#define NN 50000
#define NE 800000
#define TM 16

typedef _Float16 half4v __attribute__((ext_vector_type(4)));
typedef _Float16 half8v __attribute__((ext_vector_type(8)));
typedef float f32x4 __attribute__((ext_vector_type(4)));

__device__ __forceinline__ float relu(float v) { return fmaxf(v, 0.0f); }

// ---- degree count over dst ----
__global__ __launch_bounds__(256) void k_deg(const int* __restrict__ ei,
                                             int* __restrict__ deg) {
  int e = blockIdx.x * 256 + threadIdx.x;
  if (e < NE) atomicAdd(&deg[ei[NE + e]], 1);
}

// ---- d^-1/2 ----
__global__ __launch_bounds__(256) void k_dinv(const int* __restrict__ deg,
                                              float* __restrict__ dinv) {
  int i = blockIdx.x * 256 + threadIdx.x;
  if (i < NN) {
    int d = deg[i];
    dinv[i] = d > 0 ? 1.0f / sqrtf((float)d) : 0.0f;
  }
}

// ---- exclusive scan of deg -> rowptr (single 1024-thread block) ----
__global__ __launch_bounds__(1024) void k_scan(const int* __restrict__ deg,
                                               int* __restrict__ rowptr) {
  __shared__ int swave[16];
  __shared__ int scarry;
  const int tid = threadIdx.x;
  const int lane = tid & 63;
  const int wid = tid >> 6;
  if (tid == 0) scarry = 0;
  __syncthreads();
  for (int base = 0; base < NN; base += 1024) {
    int i = base + tid;
    int v = (i < NN) ? deg[i] : 0;
    int sum = v;
#pragma unroll
    for (int off = 1; off < 64; off <<= 1) {
      int t = __shfl_up(sum, off);
      if (lane >= off) sum += t;
    }
    if (lane == 63) swave[wid] = sum;
    __syncthreads();
    int wbase = 0;
    for (int w = 0; w < wid; ++w) wbase += swave[w];
    int carry = scarry;
    if (i < NN) rowptr[i] = carry + wbase + sum - v;
    __syncthreads();
    if (tid == 1023) scarry = carry + wbase + sum;
    __syncthreads();
  }
  if (tid == 0) rowptr[NN] = scarry;
}

// ---- CSR fill + edge weights ----
__global__ __launch_bounds__(256) void k_fill(const int* __restrict__ ei,
                                              const float* __restrict__ dinv,
                                              const int* __restrict__ rowptr,
                                              int* __restrict__ fill,
                                              int* __restrict__ col,
                                              float* __restrict__ wgt) {
  int e = blockIdx.x * 256 + threadIdx.x;
  if (e < NE) {
    int s = ei[e];
    int d = ei[NE + e];
    float w = dinv[s] * dinv[d] * 0.5f;
    int pos = rowptr[d] + atomicAdd(&fill[d], 1);
    col[pos] = s;
    wgt[pos] = w;
  }
}

// ---- x (f32) -> xh (f16) ----
__global__ __launch_bounds__(256) void k_x2h(const float* __restrict__ x,
                                             _Float16* __restrict__ xh) {
  int i = blockIdx.x * 256 + threadIdx.x;
  if (i < NN * 32) {
    float4 v = ((const float4*)x)[i];
    half4v h;
    h[0] = (_Float16)v.x; h[1] = (_Float16)v.y;
    h[2] = (_Float16)v.z; h[3] = (_Float16)v.w;
    ((half4v*)xh)[i] = h;
  }
}

// ---- one hop: 16 lanes/node, 16B row chunks, f32 accumulate ----
__global__ __launch_bounds__(256) void k_hop16(const _Float16* __restrict__ in,
                                               _Float16* __restrict__ out,
                                               const int* __restrict__ rowptr,
                                               const int* __restrict__ col,
                                               const float* __restrict__ wgt) {
  int g = (blockIdx.x * 256 + threadIdx.x) >> 4;  // node, 16 threads/node
  int lane = threadIdx.x & 15;
  if (g >= NN) return;
  const half8v* in8 = (const half8v*)in;  // 16B per lane, 256B per row
  half8v a = in8[(size_t)g * 16 + lane];
  float acc[8];
#pragma unroll
  for (int j = 0; j < 8; ++j) acc[j] = 0.5f * (float)a[j];
  int e = rowptr[g], e1 = rowptr[g + 1];
  for (; e + 4 <= e1; e += 4) {
    int c0 = col[e], c1 = col[e + 1], c2 = col[e + 2], c3 = col[e + 3];
    float w0 = wgt[e], w1 = wgt[e + 1], w2 = wgt[e + 2], w3 = wgt[e + 3];
    half8v v0 = in8[(size_t)c0 * 16 + lane];
    half8v v1 = in8[(size_t)c1 * 16 + lane];
    half8v v2 = in8[(size_t)c2 * 16 + lane];
    half8v v3 = in8[(size_t)c3 * 16 + lane];
#pragma unroll
    for (int j = 0; j < 8; ++j)
      acc[j] += w0 * (float)v0[j] + w1 * (float)v1[j] +
                w2 * (float)v2[j] + w3 * (float)v3[j];
  }
  for (; e < e1; ++e) {
    float w = wgt[e];
    half8v v = in8[(size_t)col[e] * 16 + lane];
#pragma unroll
    for (int j = 0; j < 8; ++j) acc[j] += w * (float)v[j];
  }
  half8v r;
#pragma unroll
  for (int j = 0; j < 8; ++j) r[j] = (_Float16)acc[j];
  ((half8v*)out)[(size_t)g * 16 + lane] = r;
}

// ---- prep: weights -> f16 fragment-order [m][ct(8)][ks(4)][lane(64)][8] ----
__global__ __launch_bounds__(256) void k_prep(const float* __restrict__ W_low,
                                              const float* __restrict__ W_band,
                                              const float* __restrict__ W_mlp,
                                              _Float16* __restrict__ WTs) {
  int m = blockIdx.x;  // 0..6 channels, 7..8 mlp chunks
  const float* src;
  if (m < 4)      src = W_low + m * 16384;
  else if (m < 7) src = W_band + (m - 4) * 16384;
  else            src = W_mlp + (m - 7) * 16384;
  _Float16* dst = WTs + (size_t)m * 16384;
  for (int s = threadIdx.x; s < 2048; s += 256) {
    int ct = s >> 8;          // col tile 0..7
    int ks = (s >> 6) & 3;    // k step 0..3
    int lane = s & 63;
    int mcol = lane & 15, kg = lane >> 4;
    int colc = ct * 16 + mcol;
    int k0 = ks * 32 + 4 * kg;
    _Float16* d = dst + (size_t)s * 8;
#pragma unroll
    for (int j = 0; j < 4; ++j) d[j] = (_Float16)src[(k0 + j) * 128 + colc];
#pragma unroll
    for (int j = 0; j < 4; ++j) d[4 + j] = (_Float16)src[(k0 + 16 + j) * 128 + colc];
  }
}

// A-fragment load: 4 K-steps of the mrow-th node row of `src`
#define LOADF(dst, src)                                                        \
  {                                                                            \
    const _Float16* p_ = (src) + (size_t)(node0 + mrow) * 128;                 \
    _Pragma("unroll")                                                          \
    for (int ks = 0; ks < 4; ++ks) {                                           \
      half4v lo_ = *(const half4v*)&p_[ks * 32 + 4 * kg];                      \
      half4v hi_ = *(const half4v*)&p_[ks * 32 + 4 * kg + 16];                 \
      dst[ks] = __builtin_shufflevector(lo_, hi_, 0, 1, 2, 3, 4, 5, 6, 7);     \
    }                                                                          \
  }

// One channel GEMM: f32 accumulate, bias added, packed to f16 registers
#define CH_GEMM(c, AEXPR, BIASPTR)                                             \
  {                                                                            \
    const _Float16* wc_ = WTs + (size_t)(c) * 16384;                           \
    f32x4 A0_ = {0.f, 0.f, 0.f, 0.f}, A1_ = {0.f, 0.f, 0.f, 0.f};              \
    _Pragma("unroll")                                                          \
    for (int ks = 0; ks < 4; ++ks) {                                           \
      half8v af_ = (AEXPR);                                                    \
      half8v bf0_ = *(const half8v*)&wc_[(size_t)(2 * wid) * 2048 + ks * 512 + lane * 8];     \
      half8v bf1_ = *(const half8v*)&wc_[(size_t)(2 * wid + 1) * 2048 + ks * 512 + lane * 8]; \
      A0_ = __builtin_amdgcn_mfma_f32_16x16x32_f16(af_, bf0_, A0_, 0, 0, 0);   \
      A1_ = __builtin_amdgcn_mfma_f32_16x16x32_f16(af_, bf1_, A1_, 0, 0, 0);   \
    }                                                                          \
    float bv0_ = (BIASPTR)[colw + mrow], bv1_ = (BIASPTR)[colw + 16 + mrow];   \
    half4v H0_, H1_;                                                           \
    _Pragma("unroll")                                                          \
    for (int r = 0; r < 4; ++r) {                                              \
      H0_[r] = (_Float16)(A0_[r] + bv0_);                                      \
      H1_[r] = (_Float16)(A1_[r] + bv1_);                                      \
    }                                                                          \
    h0[c] = H0_; h1[c] = H1_;                                                  \
  }

// ---- fused MFMA: 7-channel GEMM (h in f16 registers) + attention + MLP ----
__global__ __launch_bounds__(256) void k_fused(
    const _Float16* __restrict__ xh, const _Float16* __restrict__ a1,
    const _Float16* __restrict__ a2, const _Float16* __restrict__ a4,
    const _Float16* __restrict__ WTs,
    const float* __restrict__ b_low, const float* __restrict__ b_band,
    const float* __restrict__ apre_l, const float* __restrict__ ach_l,
    const float* __restrict__ apre_b, const float* __restrict__ ach_b,
    const float* __restrict__ b_mlp, float* __restrict__ out) {
  __shared__ float pD[2][TM][4];     // [low|band][node][wave] pre-dot partials
  __shared__ float pS[7][TM][4];     // [chan][node][wave] chan-dot partials
  __shared__ float aB[TM][8];        // alpha per node (7 used)
  __shared__ _Float16 sV[TM][264];   // MLP input [node][256]+pad

  const int tid = threadIdx.x;
  const int wid = tid >> 6;
  const int lane = tid & 63;
  const int mrow = lane & 15;
  const int kg = lane >> 4;
  const int node0 = blockIdx.x * TM;
  const int colw = wid * 32;

  half4v h0[7], h1[7];  // per-channel outputs (bias included), f16-packed
  half8v fA[4], fB[4];

  // rolling A-fragments; channel order shares arrays pairwise
  LOADF(fA, xh);
  CH_GEMM(0, fA[ks], b_low + 0 * 128);
  LOADF(fB, a1);
  CH_GEMM(4, fA[ks] - fB[ks], b_band + 0 * 128);
  CH_GEMM(1, fB[ks], b_low + 1 * 128);
  LOADF(fA, a2);
  CH_GEMM(5, fB[ks] - fA[ks], b_band + 1 * 128);
  CH_GEMM(2, fA[ks], b_low + 2 * 128);
  LOADF(fB, a4);
  CH_GEMM(6, fA[ks] - fB[ks], b_band + 2 * 128);
  CH_GEMM(3, fB[ks], b_low + 3 * 128);

  // ---- attention partials in-register ----
  const float apl0 = apre_l[colw + mrow], apl1 = apre_l[colw + 16 + mrow];
  const float acl0 = ach_l[colw + mrow],  acl1 = ach_l[colw + 16 + mrow];
  const float apb0 = apre_b[colw + mrow], apb1 = apre_b[colw + 16 + mrow];
  const float acb0 = ach_b[colw + mrow],  acb1 = ach_b[colw + 16 + mrow];

  float dpl[4] = {0.f, 0.f, 0.f, 0.f}, dpb[4] = {0.f, 0.f, 0.f, 0.f};
  float sc[7][4];
#pragma unroll
  for (int c = 0; c < 7; ++c) {
#pragma unroll
    for (int r = 0; r < 4; ++r) {
      float r0 = relu((float)h0[c][r]);
      float r1 = relu((float)h1[c][r]);
      if (c < 4) {
        dpl[r] += r0 * apl0 + r1 * apl1;
        sc[c][r] = r0 * acl0 + r1 * acl1;
      } else {
        dpb[r] += r0 * apb0 + r1 * apb1;
        sc[c][r] = r0 * acb0 + r1 * acb1;
      }
    }
  }
#pragma unroll
  for (int r = 0; r < 4; ++r) { dpl[r] *= 0.25f; dpb[r] *= (1.0f / 3.0f); }
  // reduce over the 16 mrow lanes (lane bits 0..3)
#pragma unroll
  for (int m = 1; m <= 8; m <<= 1) {
#pragma unroll
    for (int r = 0; r < 4; ++r) {
      dpl[r] += __shfl_xor(dpl[r], m);
      dpb[r] += __shfl_xor(dpb[r], m);
    }
#pragma unroll
    for (int c = 0; c < 7; ++c)
#pragma unroll
      for (int r = 0; r < 4; ++r) sc[c][r] += __shfl_xor(sc[c][r], m);
  }
  if (mrow == 0) {
#pragma unroll
    for (int r = 0; r < 4; ++r) {
      pD[0][4 * kg + r][wid] = dpl[r];
      pD[1][4 * kg + r][wid] = dpb[r];
#pragma unroll
      for (int c = 0; c < 7; ++c) pS[c][4 * kg + r][wid] = sc[c][r];
    }
  }
  __syncthreads();

  // ---- softmax over channels (one thread per node) ----
  if (tid < TM) {
    const int n = tid;
    float dl = pD[0][n][0] + pD[0][n][1] + pD[0][n][2] + pD[0][n][3];
    float db = pD[1][n][0] + pD[1][n][1] + pD[1][n][2] + pD[1][n][3];
    float lg[7];
#pragma unroll
    for (int c = 0; c < 7; ++c) {
      float s = pS[c][n][0] + pS[c][n][1] + pS[c][n][2] + pS[c][n][3];
      lg[c] = relu((c < 4 ? dl : db) + s);
    }
    float ml = fmaxf(fmaxf(lg[0], lg[1]), fmaxf(lg[2], lg[3]));
    float e0 = expf(lg[0] - ml), e1 = expf(lg[1] - ml);
    float e2 = expf(lg[2] - ml), e3 = expf(lg[3] - ml);
    float invl = 1.0f / (e0 + e1 + e2 + e3);
    float mb = fmaxf(fmaxf(lg[4], lg[5]), lg[6]);
    float f4 = expf(lg[4] - mb), f5 = expf(lg[5] - mb), f6 = expf(lg[6] - mb);
    float invb = 1.0f / (f4 + f5 + f6);
    aB[n][0] = e0 * invl; aB[n][1] = e1 * invl;
    aB[n][2] = e2 * invl; aB[n][3] = e3 * invl;
    aB[n][4] = f4 * invb; aB[n][5] = f5 * invb; aB[n][6] = f6 * invb;
  }
  __syncthreads();

  // ---- weighted sum straight from registers -> sV ----
#pragma unroll
  for (int r = 0; r < 4; ++r) {
    const int n = 4 * kg + r;
    float vl0 = 0.f, vl1 = 0.f, vb0 = 0.f, vb1 = 0.f;
#pragma unroll
    for (int c = 0; c < 4; ++c) {
      float a = aB[n][c];
      vl0 += a * (float)h0[c][r];
      vl1 += a * (float)h1[c][r];
    }
#pragma unroll
    for (int c = 4; c < 7; ++c) {
      float a = aB[n][c];
      vb0 += a * (float)h0[c][r];
      vb1 += a * (float)h1[c][r];
    }
    sV[n][colw + mrow] = (_Float16)vl0;
    sV[n][colw + 16 + mrow] = (_Float16)vl1;
    sV[n][128 + colw + mrow] = (_Float16)vb0;
    sV[n][128 + colw + 16 + mrow] = (_Float16)vb1;
  }
  __syncthreads();

  // ---- MLP: [TM,256] @ [256,128], coalesced B frags ----
  f32x4 m0 = {0.f, 0.f, 0.f, 0.f}, m1 = {0.f, 0.f, 0.f, 0.f};
#pragma unroll
  for (int hh = 0; hh < 2; ++hh) {
    const _Float16* wm = WTs + (size_t)(7 + hh) * 16384;
#pragma unroll
    for (int ks = 0; ks < 4; ++ks) {
      int ka = hh * 128 + ks * 32 + 4 * kg;
      half4v aa = *(const half4v*)&sV[mrow][ka];
      half4v ab = *(const half4v*)&sV[mrow][ka + 16];
      half8v af = __builtin_shufflevector(aa, ab, 0, 1, 2, 3, 4, 5, 6, 7);
      half8v bf0 = *(const half8v*)&wm[(size_t)(2 * wid) * 2048 + ks * 512 + lane * 8];
      half8v bf1 = *(const half8v*)&wm[(size_t)(2 * wid + 1) * 2048 + ks * 512 + lane * 8];
      m0 = __builtin_amdgcn_mfma_f32_16x16x32_f16(af, bf0, m0, 0, 0, 0);
      m1 = __builtin_amdgcn_mfma_f32_16x16x32_f16(af, bf1, m1, 0, 0, 0);
    }
  }
  float bm0 = b_mlp[colw + mrow];
  float bm1 = b_mlp[colw + 16 + mrow];
#pragma unroll
  for (int r = 0; r < 4; ++r) {
    out[(size_t)(node0 + 4 * kg + r) * 128 + colw + mrow] = m0[r] + bm0;
    out[(size_t)(node0 + 4 * kg + r) * 128 + colw + 16 + mrow] = m1[r] + bm1;
  }
}

extern "C" void kernel_launch(void* const* d_in, const int* in_sizes, int n_in,
                              void* d_out, int out_size, void* d_ws, size_t ws_size,
                              hipStream_t stream) {
  const float* x      = (const float*)d_in[0];
  const int* ei       = (const int*)d_in[1];
  const float* W_low  = (const float*)d_in[2];
  const float* b_low  = (const float*)d_in[3];
  const float* W_band = (const float*)d_in[4];
  const float* b_band = (const float*)d_in[5];
  const float* apre_l = (const float*)d_in[6];
  const float* ach_l  = (const float*)d_in[7];
  const float* apre_b = (const float*)d_in[8];
  const float* ach_b  = (const float*)d_in[9];
  const float* W_mlp  = (const float*)d_in[10];
  const float* b_mlp  = (const float*)d_in[11];
  float* out = (float*)d_out;

  char* ws = (char*)d_ws;
  size_t off = 0;
  auto take = [&](size_t bytes) -> void* {
    void* p = ws + off;
    off = (off + bytes + 255) & ~(size_t)255;
    return p;
  };
  int*   deg    = (int*)take((size_t)NN * 4);
  int*   fill   = (int*)take((size_t)NN * 4);
  size_t zero_bytes = off;  // deg + fill region
  float* dinv   = (float*)take((size_t)NN * 4);
  int*   rowptr = (int*)take((size_t)(NN + 1) * 4);
  int*   col    = (int*)take((size_t)NE * 4);
  float* wgt    = (float*)take((size_t)NE * 4);
  _Float16* xh  = (_Float16*)take((size_t)NN * 128 * 2);
  _Float16* a1h = (_Float16*)take((size_t)NN * 128 * 2);
  _Float16* a2h = (_Float16*)take((size_t)NN * 128 * 2);
  _Float16* a3h = (_Float16*)take((size_t)NN * 128 * 2);
  _Float16* a4h = (_Float16*)take((size_t)NN * 128 * 2);
  _Float16* WTs = (_Float16*)take((size_t)9 * 16384 * 2);
  (void)ws_size; (void)in_sizes; (void)n_in; (void)out_size;

  hipMemsetAsync(d_ws, 0, zero_bytes, stream);
  k_prep<<<9, 256, 0, stream>>>(W_low, W_band, W_mlp, WTs);
  k_x2h<<<(NN * 32 + 255) / 256, 256, 0, stream>>>(x, xh);
  k_deg<<<(NE + 255) / 256, 256, 0, stream>>>(ei, deg);
  k_dinv<<<(NN + 255) / 256, 256, 0, stream>>>(deg, dinv);
  k_scan<<<1, 1024, 0, stream>>>(deg, rowptr);
  k_fill<<<(NE + 255) / 256, 256, 0, stream>>>(ei, dinv, rowptr, fill, col, wgt);
  k_hop16<<<(NN * 16 + 255) / 256, 256, 0, stream>>>(xh,  a1h, rowptr, col, wgt);
  k_hop16<<<(NN * 16 + 255) / 256, 256, 0, stream>>>(a1h, a2h, rowptr, col, wgt);
  k_hop16<<<(NN * 16 + 255) / 256, 256, 0, stream>>>(a2h, a3h, rowptr, col, wgt);
  k_hop16<<<(NN * 16 + 255) / 256, 256, 0, stream>>>(a3h, a4h, rowptr, col, wgt);
  k_fused<<<NN / TM, 256, 0, stream>>>(xh, a1h, a2h, a4h, WTs, b_low, b_band,
                                       apre_l, ach_l, apre_b, ach_b, b_mlp, out);
}